// Round 4
// baseline (529.266 us; speedup 1.0000x reference)
//
#include <hip/hip_runtime.h>

// FastAttention (Performer linear attention), MI355X gfx950.  Round 4.
// B=4 L=4096 H=16 D=E=64 M=256, fp32 in/out, bf16 MFMA internally.
//
// R4: cooperative (non-redundant) coalesced staging + software-pipelined
// global->reg prefetch across compute; LDS trimmed to 36.4KB (k1) for
// 4 blocks/CU; grid (16,64) = exact 4/CU residency; launch_bounds(256,4).
// phi(x) = relu((x*D^-0.25) @ P^T) + 1e-3 ; scale folded into P bf16 regs.
// den folded into GEMM4 as an all-columns-equal Ksum B-operand.

#define LL 4096
#define HH 16
#define DD 64
#define EE 64
#define MM 256
#define SCALE 0.35355339059327378f  // 64^-0.25

typedef __attribute__((ext_vector_type(8))) __bf16 bf8v;
typedef __attribute__((ext_vector_type(4))) __bf16 bf4v;
typedef __attribute__((ext_vector_type(4))) float f4v;

__device__ __forceinline__ __bf16 f2bf(float f) {
  union { float f; unsigned u; } x; x.f = f;
  unsigned r = (x.u + 0x7FFFu + ((x.u >> 16) & 1u)) >> 16;
  union { unsigned short s; __bf16 b; } y; y.s = (unsigned short)r;
  return y.b;
}

#define MFMA16(a, b, c) __builtin_amdgcn_mfma_f32_16x16x32_bf16(a, b, c, 0, 0, 0)

// ws layout (floats): [ KVt: 64bh * 64e * 256m ][ Ksum: 64bh * 256m ]
#define KV_ELEMS (64 * 64 * 256)
#define KSUM_OFF KV_ELEMS
#define WS_ZERO_BYTES ((size_t)(KV_ELEMS + 64 * 256) * 4)

// ---------------------------------------------------------------------------
// Kernel 1: KVt[bh][e][m] += phi(k)^T v ; Ksum[bh][m].
// grid (16, 64), 256 thr, 4 iters of 64 rows. Wave owns m-band 64w..64w+63.
// Pipeline per iter: [sync] cvt+store prefetched tile -> LDS [sync]
//                    issue loads(it+1) ; compute GEMM1/GEMM2 in 2 mt-phases.
// kft transpose buffer halved (32 m-rows per wave, reused across phases).
// ---------------------------------------------------------------------------
__global__ __launch_bounds__(256, 4)
void k1_kv(const float* __restrict__ kin, const float* __restrict__ vin,
           const float* __restrict__ pin, float* __restrict__ ws) {
  __shared__ __bf16 kt[64 * 72];      // k tile [l][d]
  __shared__ __bf16 vt[64 * 68];      // v tile [l][e]
  __shared__ __bf16 kft[4 * 32 * 72]; // wave-private phi(k)^T half [m32][l]

  const int tid = threadIdx.x;
  const int wave = tid >> 6;
  const int lane = tid & 63;
  const int qd = lane >> 4;
  const int nn = lane & 15;
  const int bh = blockIdx.y;
  const int b = bh >> 4, h = bh & 15;
  const int l0 = blockIdx.x * 256;

  __bf16* kftw = kft + wave * (32 * 72);

  // P fragments (B-op of GEMM1): rows m = 64*wave + mt*16 + nn, k d = c*32+qd*8+j.
  bf8v pf[4][2];
#pragma unroll
  for (int mt = 0; mt < 4; ++mt) {
    const float* pr = pin + (size_t)(64 * wave + mt * 16 + nn) * DD;
#pragma unroll
    for (int c = 0; c < 2; ++c) {
      bf8v t;
#pragma unroll
      for (int j = 0; j < 8; ++j) t[j] = f2bf(pr[c * 32 + qd * 8 + j] * SCALE);
      pf[mt][c] = t;
    }
  }

  f4v acc[4][4];  // [mt][et]: rows m = 64w+mt*16+4qd+r, cols e = et*16+nn
#pragma unroll
  for (int i = 0; i < 4; ++i)
#pragma unroll
    for (int j = 0; j < 4; ++j) acc[i][j] = (f4v){0.f, 0.f, 0.f, 0.f};
  float ksum[4] = {0.f, 0.f, 0.f, 0.f};

  const size_t bhbase = (size_t)b * LL * HH * DD + (size_t)h * DD;
  // staging map: step s covers rows s*16 + (tid>>4), cols (tid&15)*4..+3
  // -> per wave-instr: 4 consecutive rows, full 256B each (8x128B lines).
  const int srow = tid >> 4;        // 0..15
  const int scol = (tid & 15) * 4;  // 0..60

  // prefetch tile 0
  f4v kr[4], vr[4];
#pragma unroll
  for (int s = 0; s < 4; ++s) {
    const size_t g = bhbase + (size_t)(l0 + s * 16 + srow) * (HH * DD) + scol;
    kr[s] = *(const f4v*)(kin + g);
    vr[s] = *(const f4v*)(vin + g);
  }

  for (int it = 0; it < 4; ++it) {
    __syncthreads();  // previous iter's kt/vt readers done
#pragma unroll
    for (int s = 0; s < 4; ++s) {
      bf4v xk, xv;
#pragma unroll
      for (int j = 0; j < 4; ++j) { xk[j] = f2bf(kr[s][j]); xv[j] = f2bf(vr[s][j]); }
      *(bf4v*)&kt[(s * 16 + srow) * 72 + scol] = xk;
      *(bf4v*)&vt[(s * 16 + srow) * 68 + scol] = xv;
    }
    __syncthreads();  // kt/vt ready for all waves

    if (it < 3) {  // loads for it+1 in flight across the whole compute phase
#pragma unroll
      for (int s = 0; s < 4; ++s) {
        const size_t g =
            bhbase + (size_t)(l0 + (it + 1) * 64 + s * 16 + srow) * (HH * DD) + scol;
        kr[s] = *(const f4v*)(kin + g);
        vr[s] = *(const f4v*)(vin + g);
      }
    }

#pragma unroll
    for (int ph = 0; ph < 2; ++ph) {  // mt phases {0,1} then {2,3}
      // ---- GEMM1 half: C[l][m] = kt . P^T ; phi ; ksum ; kft write ----
#pragma unroll
      for (int lt = 0; lt < 4; ++lt) {
        bf8v a0 = *(const bf8v*)&kt[(lt * 16 + nn) * 72 + qd * 8];
        bf8v a1 = *(const bf8v*)&kt[(lt * 16 + nn) * 72 + 32 + qd * 8];
#pragma unroll
        for (int mh = 0; mh < 2; ++mh) {
          const int mt = 2 * ph + mh;
          f4v cc = (f4v){0.f, 0.f, 0.f, 0.f};
          cc = MFMA16(a0, pf[mt][0], cc);
          cc = MFMA16(a1, pf[mt][1], cc);
          // lane: rows l = lt*16+4qd+r, col m(band) = mt*16+nn
          bf4v pk;
#pragma unroll
          for (int r = 0; r < 4; ++r) {
            float p = fmaxf(cc[r], 0.f) + 1e-3f;
            ksum[mt] += p;
            pk[r] = f2bf(p);
          }
          *(bf4v*)&kftw[(mh * 16 + nn) * 72 + lt * 16 + qd * 4] = pk;
        }
      }
      // ---- GEMM2 half: acc[mt][et] += kft_half . v ----
#pragma unroll
      for (int c = 0; c < 2; ++c) {
        bf8v af[2];
#pragma unroll
        for (int mh = 0; mh < 2; ++mh)
          af[mh] = *(const bf8v*)&kftw[(mh * 16 + nn) * 72 + c * 32 + qd * 8];
#pragma unroll
        for (int et = 0; et < 4; ++et) {
          bf8v bv;
#pragma unroll
          for (int j = 0; j < 8; ++j) bv[j] = vt[(c * 32 + qd * 8 + j) * 68 + et * 16 + nn];
#pragma unroll
          for (int mh = 0; mh < 2; ++mh)
            acc[2 * ph + mh][et] = MFMA16(af[mh], bv, acc[2 * ph + mh][et]);
        }
      }
    }
  }

  // ---- epilogue: atomic-accumulate KVt[bh][e][m] and Ksum[bh][m] ----
  float* kvb = ws + (size_t)bh * (64 * 256);
#pragma unroll
  for (int mt = 0; mt < 4; ++mt)
#pragma unroll
    for (int et = 0; et < 4; ++et)
#pragma unroll
      for (int r = 0; r < 4; ++r) {
        int m = 64 * wave + mt * 16 + 4 * qd + r;
        int e = et * 16 + nn;
        atomicAdd(&kvb[e * 256 + m], acc[mt][et][r]);
      }
#pragma unroll
  for (int mt = 0; mt < 4; ++mt) {
    float s = ksum[mt];
    s += __shfl_xor(s, 16, 64);
    s += __shfl_xor(s, 32, 64);
    if (lane < 16) atomicAdd(&ws[KSUM_OFF + bh * 256 + 64 * wave + mt * 16 + lane], s);
  }
}

// ---------------------------------------------------------------------------
// Kernel 3: out = (phi(q) @ KV) / (phi(q) . (Ksum+1e-6)).
// grid (16, 64), 256 thr, 4 iters of 64 rows, 2 barriers/iter (qf exchange).
// q B-frags direct global, 1-deep prefetch over lt; den via extra MFMA.
// ---------------------------------------------------------------------------
__global__ __launch_bounds__(256, 4)
void k3_out(const float* __restrict__ qin, const float* __restrict__ pin,
            const float* __restrict__ ws, float* __restrict__ out) {
  __shared__ __bf16 qf[64 * 264];  // phi(q) [l][m], cross-wave

  const int tid = threadIdx.x;
  const int wave = tid >> 6;
  const int lane = tid & 63;
  const int qd = lane >> 4;
  const int nn = lane & 15;
  const int bh = blockIdx.y;
  const int b = bh >> 4, h = bh & 15;
  const int l0 = blockIdx.x * 256;

  // P fragments (A-op of GEMM3'): rows m = 64w+mt*16+nn.
  bf8v pf[4][2];
#pragma unroll
  for (int mt = 0; mt < 4; ++mt) {
    const float* pr = pin + (size_t)(64 * wave + mt * 16 + nn) * DD;
#pragma unroll
    for (int c = 0; c < 2; ++c) {
      bf8v t;
#pragma unroll
      for (int j = 0; j < 8; ++j) t[j] = f2bf(pr[c * 32 + qd * 8 + j] * SCALE);
      pf[mt][c] = t;
    }
  }

  // KV B-frags: e = 16*wave + nn, k m = c*32 + qd*8 + j.
  const float* kvb = ws + (size_t)bh * (64 * 256);
  bf8v kvf[8];
#pragma unroll
  for (int c = 0; c < 8; ++c) {
    const float* src = kvb + (size_t)(16 * wave + nn) * 256 + c * 32 + qd * 8;
    bf8v t;
#pragma unroll
    for (int j = 0; j < 8; ++j) t[j] = f2bf(src[j]);
    kvf[c] = t;
  }
  // den B-frags: every column holds ksume[k] -> C columns all hold den[l].
  bf8v kvd[8];
#pragma unroll
  for (int c = 0; c < 8; ++c) {
    const float* src = ws + KSUM_OFF + bh * 256 + c * 32 + qd * 8;
    f4v s0 = *(const f4v*)src, s1 = *(const f4v*)(src + 4);
    bf8v t;
#pragma unroll
    for (int j = 0; j < 4; ++j) {
      t[j] = f2bf(s0[j] + 1e-6f);
      t[j + 4] = f2bf(s1[j] + 1e-6f);
    }
    kvd[c] = t;
  }

  const size_t bhbase = (size_t)b * LL * HH * DD + (size_t)h * DD;

  for (int it = 0; it < 4; ++it) {
    const int lt0 = l0 + it * 64;

    // ---- GEMM3': C[m][l] = P . q^T ; phi ; qf[l][m] (q 1-deep prefetch) ----
    f4v qa[4];
    {
      const float* qrow = qin + bhbase + (size_t)(lt0 + nn) * (HH * DD) + qd * 8;
      qa[0] = *(const f4v*)(qrow);
      qa[1] = *(const f4v*)(qrow + 4);
      qa[2] = *(const f4v*)(qrow + 32);
      qa[3] = *(const f4v*)(qrow + 36);
    }
#pragma unroll
    for (int lt = 0; lt < 4; ++lt) {
      f4v qn[4];
      if (lt < 3) {
        const float* qrow =
            qin + bhbase + (size_t)(lt0 + (lt + 1) * 16 + nn) * (HH * DD) + qd * 8;
        qn[0] = *(const f4v*)(qrow);
        qn[1] = *(const f4v*)(qrow + 4);
        qn[2] = *(const f4v*)(qrow + 32);
        qn[3] = *(const f4v*)(qrow + 36);
      }
      bf8v b0, b1;
#pragma unroll
      for (int j = 0; j < 4; ++j) {
        b0[j] = f2bf(qa[0][j]); b0[j + 4] = f2bf(qa[1][j]);
        b1[j] = f2bf(qa[2][j]); b1[j + 4] = f2bf(qa[3][j]);
      }
#pragma unroll
      for (int mt = 0; mt < 4; ++mt) {
        f4v cc = (f4v){0.f, 0.f, 0.f, 0.f};
        cc = MFMA16(pf[mt][0], b0, cc);
        cc = MFMA16(pf[mt][1], b1, cc);
        // lane: rows m = 64w+mt*16+4qd+r, col l = lt*16+nn
        bf4v pk;
#pragma unroll
        for (int r = 0; r < 4; ++r) pk[r] = f2bf(fmaxf(cc[r], 0.f) + 1e-3f);
        *(bf4v*)&qf[(lt * 16 + nn) * 264 + 64 * wave + mt * 16 + 4 * qd] = pk;
      }
#pragma unroll
      for (int s = 0; s < 4; ++s) qa[s] = qn[s];
    }
    __syncthreads();

    // ---- GEMM4 (+ den): out rows l = lt*16+4qd+r, col e = 16w+nn ----
#pragma unroll
    for (int lt = 0; lt < 4; ++lt) {
      f4v co = (f4v){0.f, 0.f, 0.f, 0.f};
      f4v cd = (f4v){0.f, 0.f, 0.f, 0.f};
#pragma unroll
      for (int c = 0; c < 8; ++c) {
        bf8v af = *(const bf8v*)&qf[(lt * 16 + nn) * 264 + c * 32 + qd * 8];
        co = MFMA16(af, kvf[c], co);
        cd = MFMA16(af, kvd[c], cd);
      }
#pragma unroll
      for (int r = 0; r < 4; ++r) {
        int lrel = lt * 16 + 4 * qd + r;
        int labs = lt0 + lrel;
        out[((size_t)((size_t)b * LL + labs) * HH + h) * EE + 16 * wave + nn] =
            co[r] / cd[r];
      }
    }
    __syncthreads();
  }
}

extern "C" void kernel_launch(void* const* d_in, const int* in_sizes, int n_in,
                              void* d_out, int out_size, void* d_ws, size_t ws_size,
                              hipStream_t stream) {
  (void)in_sizes; (void)n_in; (void)out_size;
  const float* q = (const float*)d_in[0];
  const float* k = (const float*)d_in[1];
  const float* v = (const float*)d_in[2];
  const float* p = (const float*)d_in[3];
  float* ws = (float*)d_ws;
  float* out = (float*)d_out;

  if (ws_size < WS_ZERO_BYTES) return;

  hipMemsetAsync(d_ws, 0, WS_ZERO_BYTES, stream);
  dim3 blk(256);
  k1_kv<<<dim3(16, 64), blk, 0, stream>>>(k, v, p, ws);
  k3_out<<<dim3(16, 64), blk, 0, stream>>>(q, p, ws, out);
}